// Round 19
// baseline (57.554 us; speedup 1.0000x reference)
//
#include <hip/hip_runtime.h>

typedef _Float16 f16;
typedef _Float16 f16x8 __attribute__((ext_vector_type(8)));
typedef short s16x8 __attribute__((ext_vector_type(8)));      // 8 bf16 in 4 VGPRs
typedef float f32x4 __attribute__((ext_vector_type(4)));
typedef float f32x16 __attribute__((ext_vector_type(16)));
typedef unsigned int u32x4 __attribute__((ext_vector_type(4)));

#define SM_OFF_NAT 11.0903548889f   // fixed softmax offset, natural units (=16*ln2)
#define MFMA32F16(a, b, c) __builtin_amdgcn_mfma_f32_32x32x16_f16(a, b, c, 0, 0, 0)
#define MFMA32BF16(a, b, c) __builtin_amdgcn_mfma_f32_32x32x16_bf16(a, b, c, 0, 0, 0)

typedef __attribute__((address_space(1))) const unsigned int* gas_t;
typedef __attribute__((address_space(3))) unsigned int* las_t;

// async global->LDS, 16B per lane: LDS dest = wave-uniform base + lane*16
static __device__ inline void gload16(const void* g, void* l) {
    __builtin_amdgcn_global_load_lds((gas_t)g, (las_t)l, 16, 0, 0);
}

// v_permlane32_swap_b32: a' = [a.row0 | b.row0], b' = [a.row1 | b.row1]
static __device__ inline void perm32swap(unsigned int& a, unsigned int& b) {
    asm("v_permlane32_swap_b32 %0, %1" : "+v"(a), "+v"(b));
}

// pack two f32 -> one u32 of two bf16. ONLY safe for non-TRANS producers
// (MFMA/VALU results) — see hazard note.
static __device__ inline unsigned int cvt_pk_bf16(float a, float b) {
    unsigned int r;
    asm("v_cvt_pk_bf16_f32 %0, %1, %2" : "=v"(r) : "v"(a), "v"(b));
    return r;
}

// HAZARD MODEL (r9..r15, confirmed): gfx950 TRANS ops (v_exp_f32) need wait
// states before a dependent consumer; the compiler protects ITS OWN consumers
// but not inline-asm reads. No inline asm may consume a TRANS result.
// Truncating bf16 pack via the v_perm builtin (hazard-protected); p rel err
// <= 2^-8 cancels between PV numerator and the ones-MFMA l.
static __device__ inline unsigned int pack_bf16_pair_trunc(float a, float b) {
    return __builtin_amdgcn_perm(__builtin_bit_cast(unsigned int, b),
                                 __builtin_bit_cast(unsigned int, a),
                                 0x07060302u);  // {b.b3,b.b2,a.b3,a.b2}
}

// scalar f32 -> bf16 (RNE)
static __device__ inline unsigned short f2bf(float f) {
    unsigned int u = __builtin_bit_cast(unsigned int, f);
    u += 0x7FFFu + ((u >> 16) & 1u);
    return (unsigned short)(u >> 16);
}

// ---------------- Kernel 0: weight prep (r17-proven) ----------------
__global__ __launch_bounds__(256) void prep_kernel(
    const float* __restrict__ Kf, const float* __restrict__ Kg,
    const float* __restrict__ Kh, const float* __restrict__ bf,
    const float* __restrict__ bg, const float* __restrict__ bh,
    f16* __restrict__ Wt16, float* __restrict__ biasG)
{
    const int tid = blockIdx.x * 256 + threadIdx.x;     // 24 blocks -> 6144
    if (tid < 6144) {
        const int c = tid >> 6, d = tid & 63;
        float v = 0.f;
        if (c < 16)      { if (c < 8)       v = Kf[d * 8 + c]; }
        else if (c < 32) { if (c - 16 < 8)  v = Kg[d * 8 + (c - 16)]; }
        else             v = Kh[d * 64 + (c - 32)];
        Wt16[tid] = (f16)v;
    }
    if (tid < 96) {
        float bv;
        if (tid < 8)        bv = bf[tid];
        else if (tid == 8)  bv = 1.0f;
        else if (tid < 16)  bv = 0.f;
        else if (tid < 24)  bv = bg[tid - 16];
        else if (tid == 24) bv = -SM_OFF_NAT;
        else if (tid < 32)  bv = 0.f;
        else                bv = bh[tid - 32];
        biasG[tid] = bv;
    }
}

// ---------------- Kernel 1: projections via MFMA (r17-proven) ----------------
__global__ __launch_bounds__(256) void projm_kernel(
    const float* __restrict__ x, const f16* __restrict__ Wt16,
    const float* __restrict__ biasG,
    f16* __restrict__ fO, f16* __restrict__ gO, unsigned short* __restrict__ hF)
{
    const int tid  = threadIdx.x;
    const int w    = tid >> 6;
    const int lane = tid & 63;
    const int c    = lane & 31;
    const int hi   = lane >> 5;

    const int pxb = (blockIdx.x * 4 + w) * 32;
    const int px  = pxb + c;

    f16x8 xa[4];
#pragma unroll
    for (int ks = 0; ks < 4; ++ks) {
        const float4* p = (const float4*)(x + (size_t)px * 64 + ks * 16 + hi * 8);
        const float4 a = p[0], bq = p[1];
        u32x4 u;
        u[0] = __builtin_bit_cast(unsigned int, __builtin_amdgcn_cvt_pkrtz(a.x, a.y));
        u[1] = __builtin_bit_cast(unsigned int, __builtin_amdgcn_cvt_pkrtz(a.z, a.w));
        u[2] = __builtin_bit_cast(unsigned int, __builtin_amdgcn_cvt_pkrtz(bq.x, bq.y));
        u[3] = __builtin_bit_cast(unsigned int, __builtin_amdgcn_cvt_pkrtz(bq.z, bq.w));
        xa[ks] = __builtin_bit_cast(f16x8, u);
    }

    f32x16 acc0, acc1, acc2;
#pragma unroll
    for (int i = 0; i < 16; ++i) { acc0[i] = 0.f; acc1[i] = 0.f; acc2[i] = 0.f; }
#pragma unroll
    for (int ks = 0; ks < 4; ++ks) {
        const f16* wb = Wt16 + (size_t)ks * 16 + hi * 8 + (size_t)c * 64;
        const f16x8 w0 = *(const f16x8*)(wb);
        const f16x8 w1 = *(const f16x8*)(wb + 32 * 64);
        const f16x8 w2 = *(const f16x8*)(wb + 64 * 64);
        acc0 = MFMA32F16(xa[ks], w0, acc0);
        acc1 = MFMA32F16(xa[ks], w1, acc1);
        acc2 = MFMA32F16(xa[ks], w2, acc2);
    }

    const float b0 = biasG[c], b1 = biasG[32 + c], b2 = biasG[64 + c];

    f16* base0 = (c < 16) ? (fO + c) : (gO + (c - 16));
#pragma unroll
    for (int r = 0; r < 16; ++r) {
        const int prow = (r & 3) + 8 * (r >> 2) + 4 * hi;
        base0[(size_t)(pxb + prow) * 16] = (f16)(acc0[r] + b0);
    }

    const int bb = pxb >> 12;
    const size_t hb0 = (size_t)bb * 262144;
#pragma unroll
    for (int t = 0; t < 2; ++t) {
        const int hc = t * 32 + c;
        const size_t hchunk = (size_t)(hc >> 5) * 512 + (size_t)(hc & 31) * 8;
        const float bt = (t == 0) ? b1 : b2;
#pragma unroll
        for (int r = 0; r < 16; ++r) {
            const int prow = (r & 3) + 8 * (r >> 2) + 4 * hi;
            const int n = (pxb & 4095) + prow;
            const float v = ((t == 0) ? acc1[r] : acc2[r]) + bt;
            hF[hb0 + (size_t)(n >> 4) * 1024 + (size_t)((n >> 3) & 1) * 256
               + hchunk + (n & 7)] = f2bf(v);
        }
    }
}

// ---------------- Kernel 2: flash attention (ring-3, counted vmcnt) ----------
// vs r18: 3-deep LDS h ring; stage h(t+2) at iter t; barrier = s_waitcnt
// vmcnt(4) lgkmcnt(0) + raw s_barrier (allows newest 4 VMEM ops — h(t+2)x2 +
// f(t+1)x2 — to remain in flight; in-order vmcnt semantics guarantee h(t+1)
// and f(t) landed). No full drain per iteration. Per-wave VMEM ops/iter are
// uniformly 4, so the literal count is exact. Tail stage index clamped.
template<int NSPLIT>
__global__ __launch_bounds__(256, 4) void attn19_kernel(
    const f16* __restrict__ fO, const f16* __restrict__ gO,
    const unsigned short* __restrict__ hF, const float* __restrict__ x,
    const float* __restrict__ gamma, float* __restrict__ out,
    unsigned short* __restrict__ po, float* __restrict__ pml)
{
    __shared__ __align__(16) char lds[3][8192];   // ring of h tiles

    const int tid  = threadIdx.x;
    const int w    = tid >> 6;
    const int lane = tid & 63;
    const int q5   = lane & 31;
    const int hi   = lane >> 5;

    const int b = blockIdx.x & 7;
    int kc, qt;
    if (NSPLIT == 8)      { kc = (blockIdx.x >> 3) & 7; qt = blockIdx.x >> 6; }
    else if (NSPLIT == 4) { kc = (blockIdx.x >> 3) & 3; qt = blockIdx.x >> 5; }
    else if (NSPLIT == 2) { kc = (blockIdx.x >> 3) & 1; qt = blockIdx.x >> 4; }
    else                  { kc = 0;                     qt = blockIdx.x >> 3; }

    const int KEYS = 4096 / NSPLIT;
    const int NIT  = KEYS / 64;
    const int k0   = kc * KEYS;
    const int qrow = qt * 128 + w * 32 + q5;

    const char* hTile = (const char*)hF + ((size_t)b * 262144 + (size_t)k0 * 64) * 2;
    const f16*  fbase = fO + ((size_t)b * 4096 + k0) * 16;

    const f16x8 gfrag = *(const f16x8*)(gO + ((size_t)b * 4096 + qrow) * 16 + hi * 8);

    // bf16 ones for the l-MFMA A operand (0x3F80 per element)
    s16x8 ones;
#pragma unroll
    for (int i = 0; i < 8; ++i) ones[i] = (short)0x3F80;

    f32x16 acc0, acc1, accl;
#pragma unroll
    for (int i = 0; i < 16; ++i) { acc0[i] = 0.f; acc1[i] = 0.f; accl[i] = 0.f; }

#define STAGE_H(KT_, BI_) do {                                                  \
        const char* hg_ = hTile + (size_t)(KT_) * 8192 + w * 2048 + (size_t)lane * 16; \
        char* hl_ = &lds[BI_][0] + w * 2048;                                    \
        gload16(hg_, hl_);                                                      \
        gload16(hg_ + 1024, hl_ + 1024);                                        \
    } while (0)

    // counted-vmcnt barrier: newest 4 VMEM ops (this iter's h-stage + f-loads)
    // may stay in flight; everything older (h(t+1), f(t)) must be complete.
#define TILE_BARRIER() do {                                                     \
        asm volatile("s_waitcnt vmcnt(4) lgkmcnt(0)" ::: "memory");             \
        __builtin_amdgcn_s_barrier();                                           \
    } while (0)

    // ---- prologue: stage h tiles 0,1; prefetch f tile 0 to regs ----
    STAGE_H(0, 0);
    STAGE_H(1, 1);
    f16x8 faA = *(const f16x8*)(fbase + (size_t)q5 * 16 + hi * 8);         // keys 0..31
    f16x8 faB = *(const f16x8*)(fbase + (size_t)(32 + q5) * 16 + hi * 8);  // keys 32..63
    TILE_BARRIER();   // h(0) done (h(1)+f(0) may fly; f(0) drained at QK(0) by compiler)

    for (int t = 0; t < NIT; ++t) {
        const int cur = t % 3;
        {   // stage h(t+2) into ring slot (t+2)%3 (clamped at tail: restage last)
            const int kt = (t + 2 < NIT) ? t + 2 : NIT - 1;
            STAGE_H(kt, (t + 2) % 3);
        }

        const f16x8 fa0 = faA, fa1 = faB;
        {   // register-prefetch f tile t+1 (clamped; compiler waits at use)
            const int ft = (t + 1 < NIT) ? t + 1 : NIT - 1;
            const f16* fp = fbase + (size_t)(ft * 64 + q5) * 16 + hi * 8;
            faA = *(const f16x8*)(fp);
            faB = *(const f16x8*)(fp + 512);        // +32 rows * 16 f16
        }

        // ---- QK^T: s[reg] = S[key][q] - 11.09 (natural units), q = lane&31 ----
        f32x16 zc;
#pragma unroll
        for (int i = 0; i < 16; ++i) zc[i] = 0.f;
        __builtin_amdgcn_s_setprio(1);
        f32x16 s0 = MFMA32F16(fa0, gfrag, zc);
        f32x16 s1 = MFMA32F16(fa1, gfrag, zc);
        __builtin_amdgcn_s_setprio(0);

        // ---- fixed-offset softmax: p = __expf(s) (native v_mul+v_exp) ----
#pragma unroll
        for (int i = 0; i < 16; ++i) {
            s0[i] = __expf(s0[i]);
            s1[i] = __expf(s1[i]);
        }

        // ---- pack to bf16 pairs via v_perm builtin (truncating; hazard-safe) ----
        unsigned int wr[16];
#pragma unroll
        for (int i = 0; i < 8; ++i) {
            wr[i]     = pack_bf16_pair_trunc(s0[2 * i], s0[2 * i + 1]);
            wr[8 + i] = pack_bf16_pair_trunc(s1[2 * i], s1[2 * i + 1]);
        }

        // ---- assemble PV B-fragments in-register: 8 permlane32_swap ----
        perm32swap(wr[0], wr[2]);   perm32swap(wr[1], wr[3]);    // keys  0..15
        perm32swap(wr[4], wr[6]);   perm32swap(wr[5], wr[7]);    // keys 16..31
        perm32swap(wr[8], wr[10]);  perm32swap(wr[9], wr[11]);   // keys 32..47
        perm32swap(wr[12], wr[14]); perm32swap(wr[13], wr[15]);  // keys 48..63

        // ---- PV + l: O^T[c][q] += H^T[c][k] P^T[k][q]; l via ones-MFMA ----
        const unsigned short* hl = (const unsigned short*)&lds[cur][0];
        __builtin_amdgcn_s_setprio(1);
#pragma unroll
        for (int kk = 0; kk < 4; ++kk) {
            u32x4 tv;
            tv[0] = wr[kk * 4 + 0]; tv[1] = wr[kk * 4 + 1];
            tv[2] = wr[kk * 4 + 2]; tv[3] = wr[kk * 4 + 3];
            const s16x8 pf = __builtin_bit_cast(s16x8, tv);
            const s16x8 ha0 = *(const s16x8*)(hl + kk * 1024 + lane * 8);
            const s16x8 ha1 = *(const s16x8*)(hl + kk * 1024 + 512 + lane * 8);
            acc0 = MFMA32BF16(ha0, pf, acc0);
            acc1 = MFMA32BF16(ha1, pf, acc1);
            accl = MFMA32BF16(ones, pf, accl);   // all rows = running l[q]
        }
        __builtin_amdgcn_s_setprio(0);

        if (t + 1 < NIT) TILE_BARRIER();   // h(t+1) ready; deeper ops stay in flight
    }
#undef STAGE_H
#undef TILE_BARRIER

    const float lpart = accl[0];            // complete over both lane halves

    if (NSPLIT == 1) {
        const float rin = 1.f / lpart;
        const float gm = gamma[0];
        const size_t qg = (size_t)b * 4096 + qrow;
#pragma unroll
        for (int cb = 0; cb < 2; ++cb)
#pragma unroll
            for (int r = 0; r < 4; ++r) {
                const size_t o = qg * 64 + cb * 32 + r * 8 + hi * 4;
                f32x4 v;
#pragma unroll
                for (int j = 0; j < 4; ++j) {
                    const float a = (cb == 0) ? acc0[4 * r + j] : acc1[4 * r + j];
                    v[j] = fmaf(gm, a * rin, x[o + j]);
                }
                *(f32x4*)(out + o) = v;
            }
    } else {
        unsigned short* pob = po + (size_t)((kc * 8 + b) * 128 + qt * 4 + w) * 2048;
#pragma unroll
        for (int cb = 0; cb < 2; ++cb)
#pragma unroll
            for (int r = 0; r < 4; ++r) {
                uint2 v;
                const float a0 = (cb == 0) ? acc0[4 * r + 0] : acc1[4 * r + 0];
                const float a1 = (cb == 0) ? acc0[4 * r + 1] : acc1[4 * r + 1];
                const float a2 = (cb == 0) ? acc0[4 * r + 2] : acc1[4 * r + 2];
                const float a3 = (cb == 0) ? acc0[4 * r + 3] : acc1[4 * r + 3];
                v.x = cvt_pk_bf16(a0, a1);      // MFMA-result consumers: asm-safe
                v.y = cvt_pk_bf16(a2, a3);
                *(uint2*)(pob + (cb * 4 + r) * 256 + lane * 4) = v;
            }
        if (lane < 32)
            pml[(size_t)(kc * 8 + b) * 4096 + qrow] = lpart;
    }
}

// ---------------- Kernel 3: split-K combine (po in bf16, shared offset) -------
template<int NS>
__global__ __launch_bounds__(256) void combine_kernel(
    const unsigned short* __restrict__ po, const float* __restrict__ pml,
    const float* __restrict__ x, const float* __restrict__ gamma,
    float* __restrict__ out)
{
    const int t    = blockIdx.x * 256 + threadIdx.x;    // 524288 threads
    const int lane = t & 63;
    const int r    = (t >> 6) & 3;
    const int cb   = (t >> 8) & 1;
    const int w    = (t >> 9) & 3;
    const int qt   = (t >> 11) & 31;
    const int b    = (t >> 16) & 7;
    const int q    = qt * 128 + w * 32 + (lane & 31);
    const int c    = cb * 32 + r * 8 + (lane >> 5) * 4;

    float denom = 0.f;
    f32x4 num;
#pragma unroll
    for (int j = 0; j < 4; ++j) num[j] = 0.f;
#pragma unroll
    for (int kc = 0; kc < NS; ++kc) {
        denom += pml[(size_t)(kc * 8 + b) * 4096 + q];
        const uint2 v = *(const uint2*)(po + (size_t)((kc * 8 + b) * 128 + qt * 4 + w) * 2048
                                           + (cb * 4 + r) * 256 + lane * 4);
        num[0] += __builtin_bit_cast(float, v.x << 16);
        num[1] += __builtin_bit_cast(float, v.x & 0xFFFF0000u);
        num[2] += __builtin_bit_cast(float, v.y << 16);
        num[3] += __builtin_bit_cast(float, v.y & 0xFFFF0000u);
    }
    const float sc = gamma[0] / denom;
    const size_t o = ((size_t)b * 4096 + q) * 64 + c;
    const f32x4 xv = *(const f32x4*)(x + o);
    f32x4 ov;
#pragma unroll
    for (int j = 0; j < 4; ++j) ov[j] = fmaf(sc, num[j], xv[j]);
    *(f32x4*)(out + o) = ov;
}

extern "C" void kernel_launch(void* const* d_in, const int* in_sizes, int n_in,
                              void* d_out, int out_size, void* d_ws, size_t ws_size,
                              hipStream_t stream) {
    const float* x     = (const float*)d_in[0];
    const float* Kf    = (const float*)d_in[1];
    const float* Kg    = (const float*)d_in[2];
    const float* Kh    = (const float*)d_in[3];
    const float* bf    = (const float*)d_in[4];
    const float* bg    = (const float*)d_in[5];
    const float* bh    = (const float*)d_in[6];
    const float* gamma = (const float*)d_in[7];
    float* out = (float*)d_out;

    f16* fO = (f16*)d_ws;                                        // 1 MB ([px][16])
    f16* gO = (f16*)((char*)d_ws + (1 << 20));                   // 1 MB ([px][16])
    unsigned short* hF = (unsigned short*)((char*)d_ws + (2 << 20)); // 4 MB bf16
    unsigned short* po = (unsigned short*)((char*)d_ws + (6 << 20)); // NSPLIT*4 MB bf16

    const size_t need4 = ((size_t)23 << 20) + (1 << 16);
    const size_t need2 = ((size_t)14 << 20) + ((size_t)1 << 19) + (1 << 16);

    if (ws_size >= need4) {
        float* pml   = (float*)((char*)d_ws + (22u << 20));
        f16*   Wt16  = (f16*)((char*)d_ws + (23u << 20));        // 12 KB
        float* biasG = (float*)((char*)d_ws + (23u << 20) + 16384);
        hipLaunchKernelGGL(prep_kernel, dim3(24), dim3(256), 0, stream,
                           Kf, Kg, Kh, bf, bg, bh, Wt16, biasG);
        hipLaunchKernelGGL(projm_kernel, dim3(256), dim3(256), 0, stream,
                           x, Wt16, biasG, fO, gO, hF);
        hipLaunchKernelGGL((attn19_kernel<4>), dim3(1024), dim3(256), 0, stream,
                           fO, gO, hF, x, gamma, out, po, pml);
        hipLaunchKernelGGL((combine_kernel<4>), dim3(2048), dim3(256), 0, stream,
                           po, pml, x, gamma, out);
    } else if (ws_size >= need2) {
        float* pml   = (float*)((char*)d_ws + (14u << 20));
        f16*   Wt16  = (f16*)((char*)d_ws + (14u << 20) + (1 << 19));
        float* biasG = (float*)((char*)d_ws + (14u << 20) + (1 << 19) + 16384);
        hipLaunchKernelGGL(prep_kernel, dim3(24), dim3(256), 0, stream,
                           Kf, Kg, Kh, bf, bg, bh, Wt16, biasG);
        hipLaunchKernelGGL(projm_kernel, dim3(256), dim3(256), 0, stream,
                           x, Wt16, biasG, fO, gO, hF);
        hipLaunchKernelGGL((attn19_kernel<2>), dim3(512), dim3(256), 0, stream,
                           fO, gO, hF, x, gamma, out, po, pml);
        hipLaunchKernelGGL((combine_kernel<2>), dim3(2048), dim3(256), 0, stream,
                           po, pml, x, gamma, out);
    } else {
        f16*   Wt16  = (f16*)((char*)d_ws + (6u << 20));
        float* biasG = (float*)((char*)d_ws + (6u << 20) + 16384);
        hipLaunchKernelGGL(prep_kernel, dim3(24), dim3(256), 0, stream,
                           Kf, Kg, Kh, bf, bg, bh, Wt16, biasG);
        hipLaunchKernelGGL(projm_kernel, dim3(256), dim3(256), 0, stream,
                           x, Wt16, biasG, fO, gO, hF);
        hipLaunchKernelGGL((attn19_kernel<1>), dim3(256), dim3(256), 0, stream,
                           fO, gO, hF, x, gamma, out, po, (float*)po);
    }
}

// Round 20
// 57.471 us; speedup vs baseline: 1.0014x; 1.0014x over previous
//
#include <hip/hip_runtime.h>

typedef _Float16 f16;
typedef _Float16 f16x8 __attribute__((ext_vector_type(8)));
typedef short s16x8 __attribute__((ext_vector_type(8)));      // 8 bf16 in 4 VGPRs
typedef float f32x4 __attribute__((ext_vector_type(4)));
typedef float f32x16 __attribute__((ext_vector_type(16)));
typedef unsigned int u32x4 __attribute__((ext_vector_type(4)));

#define SM_OFF_NAT 11.0903548889f   // fixed softmax offset, natural units (=16*ln2)
#define MFMA32F16(a, b, c) __builtin_amdgcn_mfma_f32_32x32x16_f16(a, b, c, 0, 0, 0)
#define MFMA32BF16(a, b, c) __builtin_amdgcn_mfma_f32_32x32x16_bf16(a, b, c, 0, 0, 0)

typedef __attribute__((address_space(1))) const unsigned int* gas_t;
typedef __attribute__((address_space(3))) unsigned int* las_t;

// async global->LDS, 16B per lane: LDS dest = wave-uniform base + lane*16
static __device__ inline void gload16(const void* g, void* l) {
    __builtin_amdgcn_global_load_lds((gas_t)g, (las_t)l, 16, 0, 0);
}

// v_permlane32_swap_b32: a' = [a.row0 | b.row0], b' = [a.row1 | b.row1]
static __device__ inline void perm32swap(unsigned int& a, unsigned int& b) {
    asm("v_permlane32_swap_b32 %0, %1" : "+v"(a), "+v"(b));
}

// pack two f32 -> one u32 of two bf16. ONLY safe for non-TRANS producers
// (MFMA/VALU results) — see hazard note.
static __device__ inline unsigned int cvt_pk_bf16(float a, float b) {
    unsigned int r;
    asm("v_cvt_pk_bf16_f32 %0, %1, %2" : "=v"(r) : "v"(a), "v"(b));
    return r;
}

// HAZARD MODEL (r9..r15, confirmed): gfx950 TRANS ops (v_exp_f32) need wait
// states before a dependent consumer; the compiler protects ITS OWN consumers
// but not inline-asm reads. No inline asm may consume a TRANS result.
// Truncating bf16 pack via the v_perm builtin (hazard-protected); p rel err
// <= 2^-8 cancels between PV numerator and the ones-MFMA l.
static __device__ inline unsigned int pack_bf16_pair_trunc(float a, float b) {
    return __builtin_amdgcn_perm(__builtin_bit_cast(unsigned int, b),
                                 __builtin_bit_cast(unsigned int, a),
                                 0x07060302u);  // {b.b3,b.b2,a.b3,a.b2}
}

// scalar f32 -> bf16 (RNE)
static __device__ inline unsigned short f2bf(float f) {
    unsigned int u = __builtin_bit_cast(unsigned int, f);
    u += 0x7FFFu + ((u >> 16) & 1u);
    return (unsigned short)(u >> 16);
}

// ---------------- Kernel 0: weight prep (r17-proven) ----------------
__global__ __launch_bounds__(256) void prep_kernel(
    const float* __restrict__ Kf, const float* __restrict__ Kg,
    const float* __restrict__ Kh, const float* __restrict__ bf,
    const float* __restrict__ bg, const float* __restrict__ bh,
    f16* __restrict__ Wt16, float* __restrict__ biasG)
{
    const int tid = blockIdx.x * 256 + threadIdx.x;     // 24 blocks -> 6144
    if (tid < 6144) {
        const int c = tid >> 6, d = tid & 63;
        float v = 0.f;
        if (c < 16)      { if (c < 8)       v = Kf[d * 8 + c]; }
        else if (c < 32) { if (c - 16 < 8)  v = Kg[d * 8 + (c - 16)]; }
        else             v = Kh[d * 64 + (c - 32)];
        Wt16[tid] = (f16)v;
    }
    if (tid < 96) {
        float bv;
        if (tid < 8)        bv = bf[tid];
        else if (tid == 8)  bv = 1.0f;
        else if (tid < 16)  bv = 0.f;
        else if (tid < 24)  bv = bg[tid - 16];
        else if (tid == 24) bv = -SM_OFF_NAT;
        else if (tid < 32)  bv = 0.f;
        else                bv = bh[tid - 32];
        biasG[tid] = bv;
    }
}

// ---------------- Kernel 1: projections via MFMA (r17-proven) ----------------
__global__ __launch_bounds__(256) void projm_kernel(
    const float* __restrict__ x, const f16* __restrict__ Wt16,
    const float* __restrict__ biasG,
    f16* __restrict__ fO, f16* __restrict__ gO, unsigned short* __restrict__ hF)
{
    const int tid  = threadIdx.x;
    const int w    = tid >> 6;
    const int lane = tid & 63;
    const int c    = lane & 31;
    const int hi   = lane >> 5;

    const int pxb = (blockIdx.x * 4 + w) * 32;
    const int px  = pxb + c;

    f16x8 xa[4];
#pragma unroll
    for (int ks = 0; ks < 4; ++ks) {
        const float4* p = (const float4*)(x + (size_t)px * 64 + ks * 16 + hi * 8);
        const float4 a = p[0], bq = p[1];
        u32x4 u;
        u[0] = __builtin_bit_cast(unsigned int, __builtin_amdgcn_cvt_pkrtz(a.x, a.y));
        u[1] = __builtin_bit_cast(unsigned int, __builtin_amdgcn_cvt_pkrtz(a.z, a.w));
        u[2] = __builtin_bit_cast(unsigned int, __builtin_amdgcn_cvt_pkrtz(bq.x, bq.y));
        u[3] = __builtin_bit_cast(unsigned int, __builtin_amdgcn_cvt_pkrtz(bq.z, bq.w));
        xa[ks] = __builtin_bit_cast(f16x8, u);
    }

    f32x16 acc0, acc1, acc2;
#pragma unroll
    for (int i = 0; i < 16; ++i) { acc0[i] = 0.f; acc1[i] = 0.f; acc2[i] = 0.f; }
#pragma unroll
    for (int ks = 0; ks < 4; ++ks) {
        const f16* wb = Wt16 + (size_t)ks * 16 + hi * 8 + (size_t)c * 64;
        const f16x8 w0 = *(const f16x8*)(wb);
        const f16x8 w1 = *(const f16x8*)(wb + 32 * 64);
        const f16x8 w2 = *(const f16x8*)(wb + 64 * 64);
        acc0 = MFMA32F16(xa[ks], w0, acc0);
        acc1 = MFMA32F16(xa[ks], w1, acc1);
        acc2 = MFMA32F16(xa[ks], w2, acc2);
    }

    const float b0 = biasG[c], b1 = biasG[32 + c], b2 = biasG[64 + c];

    f16* base0 = (c < 16) ? (fO + c) : (gO + (c - 16));
#pragma unroll
    for (int r = 0; r < 16; ++r) {
        const int prow = (r & 3) + 8 * (r >> 2) + 4 * hi;
        base0[(size_t)(pxb + prow) * 16] = (f16)(acc0[r] + b0);
    }

    const int bb = pxb >> 12;
    const size_t hb0 = (size_t)bb * 262144;
#pragma unroll
    for (int t = 0; t < 2; ++t) {
        const int hc = t * 32 + c;
        const size_t hchunk = (size_t)(hc >> 5) * 512 + (size_t)(hc & 31) * 8;
        const float bt = (t == 0) ? b1 : b2;
#pragma unroll
        for (int r = 0; r < 16; ++r) {
            const int prow = (r & 3) + 8 * (r >> 2) + 4 * hi;
            const int n = (pxb & 4095) + prow;
            const float v = ((t == 0) ? acc1[r] : acc2[r]) + bt;
            hF[hb0 + (size_t)(n >> 4) * 1024 + (size_t)((n >> 3) & 1) * 256
               + hchunk + (n & 7)] = f2bf(v);
        }
    }
}

// ---------------- Kernel 2: flash attention (2-tile superstep) ----------------
// vs r18: each barrier-delimited superstep processes TWO 64-key tiles (stage
// one contiguous 16KB chunk = 2 h tiles; prefetch both f sub-tiles at superstep
// start). Barrier count and staging-issue events halve; per-key work unchanged.
// Probes the "per-iteration fixed cost" hypothesis for the 42us attn floor.
template<int NSPLIT>
__global__ __launch_bounds__(256, 4) void attn20_kernel(
    const f16* __restrict__ fO, const f16* __restrict__ gO,
    const unsigned short* __restrict__ hF, const float* __restrict__ x,
    const float* __restrict__ gamma, float* __restrict__ out,
    unsigned short* __restrict__ po, float* __restrict__ pml)
{
    __shared__ __align__(16) char lds[2][16384];   // [buf][ 2 h tiles ]

    const int tid  = threadIdx.x;
    const int w    = tid >> 6;
    const int lane = tid & 63;
    const int q5   = lane & 31;
    const int hi   = lane >> 5;

    const int b = blockIdx.x & 7;
    int kc, qt;
    if (NSPLIT == 8)      { kc = (blockIdx.x >> 3) & 7; qt = blockIdx.x >> 6; }
    else if (NSPLIT == 4) { kc = (blockIdx.x >> 3) & 3; qt = blockIdx.x >> 5; }
    else if (NSPLIT == 2) { kc = (blockIdx.x >> 3) & 1; qt = blockIdx.x >> 4; }
    else                  { kc = 0;                     qt = blockIdx.x >> 3; }

    const int KEYS = 4096 / NSPLIT;
    const int NITS = KEYS / 128;                 // supersteps (2 tiles each)
    const int k0   = kc * KEYS;
    const int qrow = qt * 128 + w * 32 + q5;

    const char* hTile = (const char*)hF + ((size_t)b * 262144 + (size_t)k0 * 64) * 2;
    const f16*  fbase = fO + ((size_t)b * 4096 + k0) * 16;

    const f16x8 gfrag = *(const f16x8*)(gO + ((size_t)b * 4096 + qrow) * 16 + hi * 8);

    // bf16 ones for the l-MFMA A operand (0x3F80 per element)
    s16x8 ones;
#pragma unroll
    for (int i = 0; i < 8; ++i) ones[i] = (short)0x3F80;

    f32x16 acc0, acc1, accl;
#pragma unroll
    for (int i = 0; i < 16; ++i) { acc0[i] = 0.f; acc1[i] = 0.f; accl[i] = 0.f; }

    // stage one 16KB chunk (2 tiles): per wave 4KB at w*4096, 4 gload16/lane
#define STAGE_H2(T2_, BI_) do {                                                 \
        const char* hg_ = hTile + (size_t)(T2_) * 16384 + w * 4096 + (size_t)lane * 16; \
        char* hl_ = &lds[BI_][0] + w * 4096;                                    \
        gload16(hg_,        hl_);                                               \
        gload16(hg_ + 1024, hl_ + 1024);                                        \
        gload16(hg_ + 2048, hl_ + 2048);                                        \
        gload16(hg_ + 3072, hl_ + 3072);                                        \
    } while (0)

    // ---- prologue: stage chunk 0; prefetch both f sub-tiles of chunk 0 ----
    STAGE_H2(0, 0);
    f16x8 fa[4];                                  // [sub*2+half]
    {
        const f16* fp = fbase + (size_t)q5 * 16 + hi * 8;
        fa[0] = *(const f16x8*)(fp);
        fa[1] = *(const f16x8*)(fp + 512);
        fa[2] = *(const f16x8*)(fp + 1024);
        fa[3] = *(const f16x8*)(fp + 1536);
    }
    __syncthreads();

    for (int t2 = 0; t2 < NITS; ++t2) {
        const int cur = t2 & 1;
        const bool more = (t2 + 1) < NITS;
        if (more) STAGE_H2(t2 + 1, cur ^ 1);      // async stage next chunk

        const f16x8 c0 = fa[0], c1 = fa[1], c2 = fa[2], c3 = fa[3];
        if (more) {                               // register-prefetch next chunk's f
            const f16* fp = fbase + (size_t)((t2 + 1) * 128 + q5) * 16 + hi * 8;
            fa[0] = *(const f16x8*)(fp);
            fa[1] = *(const f16x8*)(fp + 512);
            fa[2] = *(const f16x8*)(fp + 1024);
            fa[3] = *(const f16x8*)(fp + 1536);
        }

#pragma unroll
        for (int sub = 0; sub < 2; ++sub) {
            const f16x8 fa0 = (sub == 0) ? c0 : c2;
            const f16x8 fa1 = (sub == 0) ? c1 : c3;

            // ---- QK^T: s = S[key][q] - 11.09 (natural units), q = lane&31 ----
            f32x16 zc;
#pragma unroll
            for (int i = 0; i < 16; ++i) zc[i] = 0.f;
            __builtin_amdgcn_s_setprio(1);
            f32x16 s0 = MFMA32F16(fa0, gfrag, zc);
            f32x16 s1 = MFMA32F16(fa1, gfrag, zc);
            __builtin_amdgcn_s_setprio(0);

            // ---- fixed-offset softmax: p = __expf(s) ----
#pragma unroll
            for (int i = 0; i < 16; ++i) {
                s0[i] = __expf(s0[i]);
                s1[i] = __expf(s1[i]);
            }

            // ---- pack to bf16 pairs (truncating; builtin = hazard-safe) ----
            unsigned int wr[16];
#pragma unroll
            for (int i = 0; i < 8; ++i) {
                wr[i]     = pack_bf16_pair_trunc(s0[2 * i], s0[2 * i + 1]);
                wr[8 + i] = pack_bf16_pair_trunc(s1[2 * i], s1[2 * i + 1]);
            }

            // ---- assemble PV B-fragments: 8 permlane32_swap ----
            perm32swap(wr[0], wr[2]);   perm32swap(wr[1], wr[3]);
            perm32swap(wr[4], wr[6]);   perm32swap(wr[5], wr[7]);
            perm32swap(wr[8], wr[10]);  perm32swap(wr[9], wr[11]);
            perm32swap(wr[12], wr[14]); perm32swap(wr[13], wr[15]);

            // ---- PV + l ----
            const unsigned short* hl = (const unsigned short*)&lds[cur][sub * 8192];
            __builtin_amdgcn_s_setprio(1);
#pragma unroll
            for (int kk = 0; kk < 4; ++kk) {
                u32x4 tv;
                tv[0] = wr[kk * 4 + 0]; tv[1] = wr[kk * 4 + 1];
                tv[2] = wr[kk * 4 + 2]; tv[3] = wr[kk * 4 + 3];
                const s16x8 pf = __builtin_bit_cast(s16x8, tv);
                const s16x8 ha0 = *(const s16x8*)(hl + kk * 1024 + lane * 8);
                const s16x8 ha1 = *(const s16x8*)(hl + kk * 1024 + 512 + lane * 8);
                acc0 = MFMA32BF16(ha0, pf, acc0);
                acc1 = MFMA32BF16(ha1, pf, acc1);
                accl = MFMA32BF16(ones, pf, accl);
            }
            __builtin_amdgcn_s_setprio(0);
        }

        if (more) __syncthreads();   // next chunk staged (full drain at barrier)
    }
#undef STAGE_H2

    const float lpart = accl[0];            // complete over both lane halves

    if (NSPLIT == 1) {
        const float rin = 1.f / lpart;
        const float gm = gamma[0];
        const size_t qg = (size_t)b * 4096 + qrow;
#pragma unroll
        for (int cb = 0; cb < 2; ++cb)
#pragma unroll
            for (int r = 0; r < 4; ++r) {
                const size_t o = qg * 64 + cb * 32 + r * 8 + hi * 4;
                f32x4 v;
#pragma unroll
                for (int j = 0; j < 4; ++j) {
                    const float a = (cb == 0) ? acc0[4 * r + j] : acc1[4 * r + j];
                    v[j] = fmaf(gm, a * rin, x[o + j]);
                }
                *(f32x4*)(out + o) = v;
            }
    } else {
        unsigned short* pob = po + (size_t)((kc * 8 + b) * 128 + qt * 4 + w) * 2048;
#pragma unroll
        for (int cb = 0; cb < 2; ++cb)
#pragma unroll
            for (int r = 0; r < 4; ++r) {
                uint2 v;
                const float a0 = (cb == 0) ? acc0[4 * r + 0] : acc1[4 * r + 0];
                const float a1 = (cb == 0) ? acc0[4 * r + 1] : acc1[4 * r + 1];
                const float a2 = (cb == 0) ? acc0[4 * r + 2] : acc1[4 * r + 2];
                const float a3 = (cb == 0) ? acc0[4 * r + 3] : acc1[4 * r + 3];
                v.x = cvt_pk_bf16(a0, a1);      // MFMA-result consumers: asm-safe
                v.y = cvt_pk_bf16(a2, a3);
                *(uint2*)(pob + (cb * 4 + r) * 256 + lane * 4) = v;
            }
        if (lane < 32)
            pml[(size_t)(kc * 8 + b) * 4096 + qrow] = lpart;
    }
}

// ---------------- Kernel 3: split-K combine (po in bf16, shared offset) -------
template<int NS>
__global__ __launch_bounds__(256) void combine_kernel(
    const unsigned short* __restrict__ po, const float* __restrict__ pml,
    const float* __restrict__ x, const float* __restrict__ gamma,
    float* __restrict__ out)
{
    const int t    = blockIdx.x * 256 + threadIdx.x;    // 524288 threads
    const int lane = t & 63;
    const int r    = (t >> 6) & 3;
    const int cb   = (t >> 8) & 1;
    const int w    = (t >> 9) & 3;
    const int qt   = (t >> 11) & 31;
    const int b    = (t >> 16) & 7;
    const int q    = qt * 128 + w * 32 + (lane & 31);
    const int c    = cb * 32 + r * 8 + (lane >> 5) * 4;

    float denom = 0.f;
    f32x4 num;
#pragma unroll
    for (int j = 0; j < 4; ++j) num[j] = 0.f;
#pragma unroll
    for (int kc = 0; kc < NS; ++kc) {
        denom += pml[(size_t)(kc * 8 + b) * 4096 + q];
        const uint2 v = *(const uint2*)(po + (size_t)((kc * 8 + b) * 128 + qt * 4 + w) * 2048
                                           + (cb * 4 + r) * 256 + lane * 4);
        num[0] += __builtin_bit_cast(float, v.x << 16);
        num[1] += __builtin_bit_cast(float, v.x & 0xFFFF0000u);
        num[2] += __builtin_bit_cast(float, v.y << 16);
        num[3] += __builtin_bit_cast(float, v.y & 0xFFFF0000u);
    }
    const float sc = gamma[0] / denom;
    const size_t o = ((size_t)b * 4096 + q) * 64 + c;
    const f32x4 xv = *(const f32x4*)(x + o);
    f32x4 ov;
#pragma unroll
    for (int j = 0; j < 4; ++j) ov[j] = fmaf(sc, num[j], xv[j]);
    *(f32x4*)(out + o) = ov;
}

extern "C" void kernel_launch(void* const* d_in, const int* in_sizes, int n_in,
                              void* d_out, int out_size, void* d_ws, size_t ws_size,
                              hipStream_t stream) {
    const float* x     = (const float*)d_in[0];
    const float* Kf    = (const float*)d_in[1];
    const float* Kg    = (const float*)d_in[2];
    const float* Kh    = (const float*)d_in[3];
    const float* bf    = (const float*)d_in[4];
    const float* bg    = (const float*)d_in[5];
    const float* bh    = (const float*)d_in[6];
    const float* gamma = (const float*)d_in[7];
    float* out = (float*)d_out;

    f16* fO = (f16*)d_ws;                                        // 1 MB ([px][16])
    f16* gO = (f16*)((char*)d_ws + (1 << 20));                   // 1 MB ([px][16])
    unsigned short* hF = (unsigned short*)((char*)d_ws + (2 << 20)); // 4 MB bf16
    unsigned short* po = (unsigned short*)((char*)d_ws + (6 << 20)); // NSPLIT*4 MB bf16

    const size_t need4 = ((size_t)23 << 20) + (1 << 16);
    const size_t need2 = ((size_t)14 << 20) + ((size_t)1 << 19) + (1 << 16);

    if (ws_size >= need4) {
        float* pml   = (float*)((char*)d_ws + (22u << 20));
        f16*   Wt16  = (f16*)((char*)d_ws + (23u << 20));        // 12 KB
        float* biasG = (float*)((char*)d_ws + (23u << 20) + 16384);
        hipLaunchKernelGGL(prep_kernel, dim3(24), dim3(256), 0, stream,
                           Kf, Kg, Kh, bf, bg, bh, Wt16, biasG);
        hipLaunchKernelGGL(projm_kernel, dim3(256), dim3(256), 0, stream,
                           x, Wt16, biasG, fO, gO, hF);
        hipLaunchKernelGGL((attn20_kernel<4>), dim3(1024), dim3(256), 0, stream,
                           fO, gO, hF, x, gamma, out, po, pml);
        hipLaunchKernelGGL((combine_kernel<4>), dim3(2048), dim3(256), 0, stream,
                           po, pml, x, gamma, out);
    } else if (ws_size >= need2) {
        float* pml   = (float*)((char*)d_ws + (14u << 20));
        f16*   Wt16  = (f16*)((char*)d_ws + (14u << 20) + (1 << 19));
        float* biasG = (float*)((char*)d_ws + (14u << 20) + (1 << 19) + 16384);
        hipLaunchKernelGGL(prep_kernel, dim3(24), dim3(256), 0, stream,
                           Kf, Kg, Kh, bf, bg, bh, Wt16, biasG);
        hipLaunchKernelGGL(projm_kernel, dim3(256), dim3(256), 0, stream,
                           x, Wt16, biasG, fO, gO, hF);
        hipLaunchKernelGGL((attn20_kernel<2>), dim3(512), dim3(256), 0, stream,
                           fO, gO, hF, x, gamma, out, po, pml);
        hipLaunchKernelGGL((combine_kernel<2>), dim3(2048), dim3(256), 0, stream,
                           po, pml, x, gamma, out);
    } else {
        f16*   Wt16  = (f16*)((char*)d_ws + (6u << 20));
        float* biasG = (float*)((char*)d_ws + (6u << 20) + 16384);
        hipLaunchKernelGGL(prep_kernel, dim3(24), dim3(256), 0, stream,
                           Kf, Kg, Kh, bf, bg, bh, Wt16, biasG);
        hipLaunchKernelGGL(projm_kernel, dim3(256), dim3(256), 0, stream,
                           x, Wt16, biasG, fO, gO, hF);
        hipLaunchKernelGGL((attn20_kernel<1>), dim3(256), dim3(256), 0, stream,
                           fO, gO, hF, x, gamma, out, po, (float*)po);
    }
}

// Round 22
// 56.799 us; speedup vs baseline: 1.0133x; 1.0118x over previous
//
#include <hip/hip_runtime.h>

typedef _Float16 f16;
typedef _Float16 f16x8 __attribute__((ext_vector_type(8)));
typedef short s16x8 __attribute__((ext_vector_type(8)));      // 8 bf16 in 4 VGPRs
typedef float f32x4 __attribute__((ext_vector_type(4)));
typedef float f32x16 __attribute__((ext_vector_type(16)));
typedef unsigned int u32x4 __attribute__((ext_vector_type(4)));

#define SM_OFF_NAT 11.0903548889f   // fixed softmax offset, natural units (=16*ln2)
#define MFMA32F16(a, b, c) __builtin_amdgcn_mfma_f32_32x32x16_f16(a, b, c, 0, 0, 0)
#define MFMA32BF16(a, b, c) __builtin_amdgcn_mfma_f32_32x32x16_bf16(a, b, c, 0, 0, 0)

typedef __attribute__((address_space(1))) const unsigned int* gas_t;
typedef __attribute__((address_space(3))) unsigned int* las_t;

// async global->LDS, 16B per lane: LDS dest = wave-uniform base + lane*16
static __device__ inline void gload16(const void* g, void* l) {
    __builtin_amdgcn_global_load_lds((gas_t)g, (las_t)l, 16, 0, 0);
}

// v_permlane32_swap_b32: a' = [a.row0 | b.row0], b' = [a.row1 | b.row1]
static __device__ inline void perm32swap(unsigned int& a, unsigned int& b) {
    asm("v_permlane32_swap_b32 %0, %1" : "+v"(a), "+v"(b));
}

// pack two f32 -> one u32 of two bf16. ONLY safe for non-TRANS producers
// (MFMA/VALU results) — see hazard note.
static __device__ inline unsigned int cvt_pk_bf16(float a, float b) {
    unsigned int r;
    asm("v_cvt_pk_bf16_f32 %0, %1, %2" : "=v"(r) : "v"(a), "v"(b));
    return r;
}

// HAZARD MODEL (r9..r21, confirmed): gfx950 TRANS ops (v_exp_f32) need wait
// states before a dependent consumer; the compiler protects ITS OWN consumers
// but not inline-asm reads. No inline asm may consume a TRANS result. Also:
// keep VGPR pressure comfortably under the launch-bounds cap — r21 showed the
// hazard class re-emerges under pressure-driven rescheduling around asm.
// Truncating bf16 pack via the v_perm builtin (hazard-protected); p rel err
// <= 2^-8 cancels between PV numerator and the ones-MFMA l.
static __device__ inline unsigned int pack_bf16_pair_trunc(float a, float b) {
    return __builtin_amdgcn_perm(__builtin_bit_cast(unsigned int, b),
                                 __builtin_bit_cast(unsigned int, a),
                                 0x07060302u);  // {b.b3,b.b2,a.b3,a.b2}
}

// scalar f32 -> bf16 (RNE)
static __device__ inline unsigned short f2bf(float f) {
    unsigned int u = __builtin_bit_cast(unsigned int, f);
    u += 0x7FFFu + ((u >> 16) & 1u);
    return (unsigned short)(u >> 16);
}

// ---------------- Kernel 0: weight prep (r17-proven) ----------------
__global__ __launch_bounds__(256) void prep_kernel(
    const float* __restrict__ Kf, const float* __restrict__ Kg,
    const float* __restrict__ Kh, const float* __restrict__ bf,
    const float* __restrict__ bg, const float* __restrict__ bh,
    f16* __restrict__ Wt16, float* __restrict__ biasG)
{
    const int tid = blockIdx.x * 256 + threadIdx.x;     // 24 blocks -> 6144
    if (tid < 6144) {
        const int c = tid >> 6, d = tid & 63;
        float v = 0.f;
        if (c < 16)      { if (c < 8)       v = Kf[d * 8 + c]; }
        else if (c < 32) { if (c - 16 < 8)  v = Kg[d * 8 + (c - 16)]; }
        else             v = Kh[d * 64 + (c - 32)];
        Wt16[tid] = (f16)v;
    }
    if (tid < 96) {
        float bv;
        if (tid < 8)        bv = bf[tid];
        else if (tid == 8)  bv = 1.0f;
        else if (tid < 16)  bv = 0.f;
        else if (tid < 24)  bv = bg[tid - 16];
        else if (tid == 24) bv = -SM_OFF_NAT;
        else if (tid < 32)  bv = 0.f;
        else                bv = bh[tid - 32];
        biasG[tid] = bv;
    }
}

// ---------------- Kernel 1: projections via MFMA (r17-proven) ----------------
__global__ __launch_bounds__(256) void projm_kernel(
    const float* __restrict__ x, const f16* __restrict__ Wt16,
    const float* __restrict__ biasG,
    f16* __restrict__ fO, f16* __restrict__ gO, unsigned short* __restrict__ hF)
{
    const int tid  = threadIdx.x;
    const int w    = tid >> 6;
    const int lane = tid & 63;
    const int c    = lane & 31;
    const int hi   = lane >> 5;

    const int pxb = (blockIdx.x * 4 + w) * 32;
    const int px  = pxb + c;

    f16x8 xa[4];
#pragma unroll
    for (int ks = 0; ks < 4; ++ks) {
        const float4* p = (const float4*)(x + (size_t)px * 64 + ks * 16 + hi * 8);
        const float4 a = p[0], bq = p[1];
        u32x4 u;
        u[0] = __builtin_bit_cast(unsigned int, __builtin_amdgcn_cvt_pkrtz(a.x, a.y));
        u[1] = __builtin_bit_cast(unsigned int, __builtin_amdgcn_cvt_pkrtz(a.z, a.w));
        u[2] = __builtin_bit_cast(unsigned int, __builtin_amdgcn_cvt_pkrtz(bq.x, bq.y));
        u[3] = __builtin_bit_cast(unsigned int, __builtin_amdgcn_cvt_pkrtz(bq.z, bq.w));
        xa[ks] = __builtin_bit_cast(f16x8, u);
    }

    f32x16 acc0, acc1, acc2;
#pragma unroll
    for (int i = 0; i < 16; ++i) { acc0[i] = 0.f; acc1[i] = 0.f; acc2[i] = 0.f; }
#pragma unroll
    for (int ks = 0; ks < 4; ++ks) {
        const f16* wb = Wt16 + (size_t)ks * 16 + hi * 8 + (size_t)c * 64;
        const f16x8 w0 = *(const f16x8*)(wb);
        const f16x8 w1 = *(const f16x8*)(wb + 32 * 64);
        const f16x8 w2 = *(const f16x8*)(wb + 64 * 64);
        acc0 = MFMA32F16(xa[ks], w0, acc0);
        acc1 = MFMA32F16(xa[ks], w1, acc1);
        acc2 = MFMA32F16(xa[ks], w2, acc2);
    }

    const float b0 = biasG[c], b1 = biasG[32 + c], b2 = biasG[64 + c];

    f16* base0 = (c < 16) ? (fO + c) : (gO + (c - 16));
#pragma unroll
    for (int r = 0; r < 16; ++r) {
        const int prow = (r & 3) + 8 * (r >> 2) + 4 * hi;
        base0[(size_t)(pxb + prow) * 16] = (f16)(acc0[r] + b0);
    }

    const int bb = pxb >> 12;
    const size_t hb0 = (size_t)bb * 262144;
#pragma unroll
    for (int t = 0; t < 2; ++t) {
        const int hc = t * 32 + c;
        const size_t hchunk = (size_t)(hc >> 5) * 512 + (size_t)(hc & 31) * 8;
        const float bt = (t == 0) ? b1 : b2;
#pragma unroll
        for (int r = 0; r < 16; ++r) {
            const int prow = (r & 3) + 8 * (r >> 2) + 4 * hi;
            const int n = (pxb & 4095) + prow;
            const float v = ((t == 0) ? acc1[r] : acc2[r]) + bt;
            hF[hb0 + (size_t)(n >> 4) * 1024 + (size_t)((n >> 3) & 1) * 256
               + hchunk + (n & 7)] = f2bf(v);
        }
    }
}

// ---------------- Kernel 2: flash attention (r18-proven best) -----------------
// ones-MFMA l, truncating pack, setprio around MFMA clusters, dbuf LDS h,
// f register-prefetch, split-K x4.
template<int NSPLIT>
__global__ __launch_bounds__(256, 4) void attn22_kernel(
    const f16* __restrict__ fO, const f16* __restrict__ gO,
    const unsigned short* __restrict__ hF, const float* __restrict__ x,
    const float* __restrict__ gamma, float* __restrict__ out,
    unsigned short* __restrict__ po, float* __restrict__ pml)
{
    __shared__ __align__(16) char lds[2][8192];   // [buf][ h tile ]

    const int tid  = threadIdx.x;
    const int w    = tid >> 6;
    const int lane = tid & 63;
    const int q5   = lane & 31;
    const int hi   = lane >> 5;

    const int b = blockIdx.x & 7;
    int kc, qt;
    if (NSPLIT == 8)      { kc = (blockIdx.x >> 3) & 7; qt = blockIdx.x >> 6; }
    else if (NSPLIT == 4) { kc = (blockIdx.x >> 3) & 3; qt = blockIdx.x >> 5; }
    else if (NSPLIT == 2) { kc = (blockIdx.x >> 3) & 1; qt = blockIdx.x >> 4; }
    else                  { kc = 0;                     qt = blockIdx.x >> 3; }

    const int KEYS = 4096 / NSPLIT;
    const int NIT  = KEYS / 64;
    const int k0   = kc * KEYS;
    const int qrow = qt * 128 + w * 32 + q5;

    const char* hTile = (const char*)hF + ((size_t)b * 262144 + (size_t)k0 * 64) * 2;
    const f16*  fbase = fO + ((size_t)b * 4096 + k0) * 16;

    const f16x8 gfrag = *(const f16x8*)(gO + ((size_t)b * 4096 + qrow) * 16 + hi * 8);

    // bf16 ones for the l-MFMA A operand (0x3F80 per element)
    s16x8 ones;
#pragma unroll
    for (int i = 0; i < 8; ++i) ones[i] = (short)0x3F80;

    f32x16 acc0, acc1, accl;
#pragma unroll
    for (int i = 0; i < 16; ++i) { acc0[i] = 0.f; acc1[i] = 0.f; accl[i] = 0.f; }

#define STAGE_H(KT_, BI_) do {                                                  \
        const char* hg_ = hTile + (size_t)(KT_) * 8192 + w * 2048 + (size_t)lane * 16; \
        char* hl_ = &lds[BI_][0] + w * 2048;                                    \
        gload16(hg_, hl_);                                                      \
        gload16(hg_ + 1024, hl_ + 1024);                                        \
    } while (0)

    // ---- prologue: stage h tile 0; prefetch f tile 0 to regs ----
    STAGE_H(0, 0);
    f16x8 faA = *(const f16x8*)(fbase + (size_t)q5 * 16 + hi * 8);         // keys 0..31
    f16x8 faB = *(const f16x8*)(fbase + (size_t)(32 + q5) * 16 + hi * 8);  // keys 32..63
    __syncthreads();

    for (int t = 0; t < NIT; ++t) {
        const int cur = t & 1;
        if (t + 1 < NIT) STAGE_H(t + 1, cur ^ 1);   // async stage next h tile

        const f16x8 fa0 = faA, fa1 = faB;
        if (t + 1 < NIT) {                          // register-prefetch next f tile
            const f16* fp = fbase + (size_t)((t + 1) * 64 + q5) * 16 + hi * 8;
            faA = *(const f16x8*)(fp);
            faB = *(const f16x8*)(fp + 512);        // +32 rows * 16 f16
        }

        // ---- QK^T: s[reg] = S[key][q] - 11.09 (natural units), q = lane&31 ----
        f32x16 zc;
#pragma unroll
        for (int i = 0; i < 16; ++i) zc[i] = 0.f;
        __builtin_amdgcn_s_setprio(1);
        f32x16 s0 = MFMA32F16(fa0, gfrag, zc);
        f32x16 s1 = MFMA32F16(fa1, gfrag, zc);
        __builtin_amdgcn_s_setprio(0);

        // ---- fixed-offset softmax: p = __expf(s) (native v_mul+v_exp) ----
#pragma unroll
        for (int i = 0; i < 16; ++i) {
            s0[i] = __expf(s0[i]);
            s1[i] = __expf(s1[i]);
        }

        // ---- pack to bf16 pairs via v_perm builtin (truncating; hazard-safe) ----
        unsigned int wr[16];
#pragma unroll
        for (int i = 0; i < 8; ++i) {
            wr[i]     = pack_bf16_pair_trunc(s0[2 * i], s0[2 * i + 1]);
            wr[8 + i] = pack_bf16_pair_trunc(s1[2 * i], s1[2 * i + 1]);
        }

        // ---- assemble PV B-fragments in-register: 8 permlane32_swap ----
        perm32swap(wr[0], wr[2]);   perm32swap(wr[1], wr[3]);    // keys  0..15
        perm32swap(wr[4], wr[6]);   perm32swap(wr[5], wr[7]);    // keys 16..31
        perm32swap(wr[8], wr[10]);  perm32swap(wr[9], wr[11]);   // keys 32..47
        perm32swap(wr[12], wr[14]); perm32swap(wr[13], wr[15]);  // keys 48..63

        // ---- PV + l: O^T[c][q] += H^T[c][k] P^T[k][q]; l via ones-MFMA ----
        const unsigned short* hl = (const unsigned short*)&lds[cur][0];
        __builtin_amdgcn_s_setprio(1);
#pragma unroll
        for (int kk = 0; kk < 4; ++kk) {
            u32x4 tv;
            tv[0] = wr[kk * 4 + 0]; tv[1] = wr[kk * 4 + 1];
            tv[2] = wr[kk * 4 + 2]; tv[3] = wr[kk * 4 + 3];
            const s16x8 pf = __builtin_bit_cast(s16x8, tv);
            const s16x8 ha0 = *(const s16x8*)(hl + kk * 1024 + lane * 8);
            const s16x8 ha1 = *(const s16x8*)(hl + kk * 1024 + 512 + lane * 8);
            acc0 = MFMA32BF16(ha0, pf, acc0);
            acc1 = MFMA32BF16(ha1, pf, acc1);
            accl = MFMA32BF16(ones, pf, accl);   // all rows = running l[q]
        }
        __builtin_amdgcn_s_setprio(0);

        if (t + 1 < NIT) __syncthreads();   // staged tile ready (full drain at barrier)
    }
#undef STAGE_H

    const float lpart = accl[0];            // complete over both lane halves

    if (NSPLIT == 1) {
        const float rin = 1.f / lpart;
        const float gm = gamma[0];
        const size_t qg = (size_t)b * 4096 + qrow;
#pragma unroll
        for (int cb = 0; cb < 2; ++cb)
#pragma unroll
            for (int r = 0; r < 4; ++r) {
                const size_t o = qg * 64 + cb * 32 + r * 8 + hi * 4;
                f32x4 v;
#pragma unroll
                for (int j = 0; j < 4; ++j) {
                    const float a = (cb == 0) ? acc0[4 * r + j] : acc1[4 * r + j];
                    v[j] = fmaf(gm, a * rin, x[o + j]);
                }
                *(f32x4*)(out + o) = v;
            }
    } else {
        unsigned short* pob = po + (size_t)((kc * 8 + b) * 128 + qt * 4 + w) * 2048;
#pragma unroll
        for (int cb = 0; cb < 2; ++cb)
#pragma unroll
            for (int r = 0; r < 4; ++r) {
                uint2 v;
                const float a0 = (cb == 0) ? acc0[4 * r + 0] : acc1[4 * r + 0];
                const float a1 = (cb == 0) ? acc0[4 * r + 1] : acc1[4 * r + 1];
                const float a2 = (cb == 0) ? acc0[4 * r + 2] : acc1[4 * r + 2];
                const float a3 = (cb == 0) ? acc0[4 * r + 3] : acc1[4 * r + 3];
                v.x = cvt_pk_bf16(a0, a1);      // MFMA-result consumers: asm-safe
                v.y = cvt_pk_bf16(a2, a3);
                *(uint2*)(pob + (cb * 4 + r) * 256 + lane * 4) = v;
            }
        if (lane < 32)
            pml[(size_t)(kc * 8 + b) * 4096 + qrow] = lpart;
    }
}

// ---------------- Kernel 3: split-K combine (po in bf16, shared offset) -------
template<int NS>
__global__ __launch_bounds__(256) void combine_kernel(
    const unsigned short* __restrict__ po, const float* __restrict__ pml,
    const float* __restrict__ x, const float* __restrict__ gamma,
    float* __restrict__ out)
{
    const int t    = blockIdx.x * 256 + threadIdx.x;    // 524288 threads
    const int lane = t & 63;
    const int r    = (t >> 6) & 3;
    const int cb   = (t >> 8) & 1;
    const int w    = (t >> 9) & 3;
    const int qt   = (t >> 11) & 31;
    const int b    = (t >> 16) & 7;
    const int q    = qt * 128 + w * 32 + (lane & 31);
    const int c    = cb * 32 + r * 8 + (lane >> 5) * 4;

    float denom = 0.f;
    f32x4 num;
#pragma unroll
    for (int j = 0; j < 4; ++j) num[j] = 0.f;
#pragma unroll
    for (int kc = 0; kc < NS; ++kc) {
        denom += pml[(size_t)(kc * 8 + b) * 4096 + q];
        const uint2 v = *(const uint2*)(po + (size_t)((kc * 8 + b) * 128 + qt * 4 + w) * 2048
                                           + (cb * 4 + r) * 256 + lane * 4);
        num[0] += __builtin_bit_cast(float, v.x << 16);
        num[1] += __builtin_bit_cast(float, v.x & 0xFFFF0000u);
        num[2] += __builtin_bit_cast(float, v.y << 16);
        num[3] += __builtin_bit_cast(float, v.y & 0xFFFF0000u);
    }
    const float sc = gamma[0] / denom;
    const size_t o = ((size_t)b * 4096 + q) * 64 + c;
    const f32x4 xv = *(const f32x4*)(x + o);
    f32x4 ov;
#pragma unroll
    for (int j = 0; j < 4; ++j) ov[j] = fmaf(sc, num[j], xv[j]);
    *(f32x4*)(out + o) = ov;
}

extern "C" void kernel_launch(void* const* d_in, const int* in_sizes, int n_in,
                              void* d_out, int out_size, void* d_ws, size_t ws_size,
                              hipStream_t stream) {
    const float* x     = (const float*)d_in[0];
    const float* Kf    = (const float*)d_in[1];
    const float* Kg    = (const float*)d_in[2];
    const float* Kh    = (const float*)d_in[3];
    const float* bf    = (const float*)d_in[4];
    const float* bg    = (const float*)d_in[5];
    const float* bh    = (const float*)d_in[6];
    const float* gamma = (const float*)d_in[7];
    float* out = (float*)d_out;

    f16* fO = (f16*)d_ws;                                        // 1 MB ([px][16])
    f16* gO = (f16*)((char*)d_ws + (1 << 20));                   // 1 MB ([px][16])
    unsigned short* hF = (unsigned short*)((char*)d_ws + (2 << 20)); // 4 MB bf16
    unsigned short* po = (unsigned short*)((char*)d_ws + (6 << 20)); // NSPLIT*4 MB bf16

    const size_t need4 = ((size_t)23 << 20) + (1 << 16);
    const size_t need2 = ((size_t)14 << 20) + ((size_t)1 << 19) + (1 << 16);

    if (ws_size >= need4) {
        float* pml   = (float*)((char*)d_ws + (22u << 20));
        f16*   Wt16  = (f16*)((char*)d_ws + (23u << 20));        // 12 KB
        float* biasG = (float*)((char*)d_ws + (23u << 20) + 16384);
        hipLaunchKernelGGL(prep_kernel, dim3(24), dim3(256), 0, stream,
                           Kf, Kg, Kh, bf, bg, bh, Wt16, biasG);
        hipLaunchKernelGGL(projm_kernel, dim3(256), dim3(256), 0, stream,
                           x, Wt16, biasG, fO, gO, hF);
        hipLaunchKernelGGL((attn22_kernel<4>), dim3(1024), dim3(256), 0, stream,
                           fO, gO, hF, x, gamma, out, po, pml);
        hipLaunchKernelGGL((combine_kernel<4>), dim3(2048), dim3(256), 0, stream,
                           po, pml, x, gamma, out);
    } else if (ws_size >= need2) {
        float* pml   = (float*)((char*)d_ws + (14u << 20));
        f16*   Wt16  = (f16*)((char*)d_ws + (14u << 20) + (1 << 19));
        float* biasG = (float*)((char*)d_ws + (14u << 20) + (1 << 19) + 16384);
        hipLaunchKernelGGL(prep_kernel, dim3(24), dim3(256), 0, stream,
                           Kf, Kg, Kh, bf, bg, bh, Wt16, biasG);
        hipLaunchKernelGGL(projm_kernel, dim3(256), dim3(256), 0, stream,
                           x, Wt16, biasG, fO, gO, hF);
        hipLaunchKernelGGL((attn22_kernel<2>), dim3(512), dim3(256), 0, stream,
                           fO, gO, hF, x, gamma, out, po, pml);
        hipLaunchKernelGGL((combine_kernel<2>), dim3(2048), dim3(256), 0, stream,
                           po, pml, x, gamma, out);
    } else {
        f16*   Wt16  = (f16*)((char*)d_ws + (6u << 20));
        float* biasG = (float*)((char*)d_ws + (6u << 20) + 16384);
        hipLaunchKernelGGL(prep_kernel, dim3(24), dim3(256), 0, stream,
                           Kf, Kg, Kh, bf, bg, bh, Wt16, biasG);
        hipLaunchKernelGGL(projm_kernel, dim3(256), dim3(256), 0, stream,
                           x, Wt16, biasG, fO, gO, hF);
        hipLaunchKernelGGL((attn22_kernel<1>), dim3(256), dim3(256), 0, stream,
                           fO, gO, hF, x, gamma, out, po, (float*)po);
    }
}